// Round 1
// baseline (33.985 us; speedup 1.0000x reference)
//
#include <hip/hip_runtime.h>
#include <hip/hip_bf16.h>
#include <stdint.h>

// GridMask, MODE=0: out = x * mask(b,h,w), broadcast over C=3.
// mask==0 iff ((OFF+h - st_h) mod d) < l  OR  ((OFF+w - st_w) mod d) < l
//   d = 96 + d_raw[b], l = ceil(d/2), st_h = st_h_raw[b] % d, st_w = st_w_raw[b] % d
// HH = ceil(sqrt(512^2+512^2)) = 725, OFF_H = OFF_W = (725-512)/2 = 106.

#define BB 32
#define HH_ 512
#define WW 512
#define CC 3
#define D1_ 96
#define OFFC 106
#define ROW_FLOATS (WW * CC)   // 1536 floats per (b,h) row, 6144 B (16B aligned)

__global__ __launch_bounds__(384) void gridmask_kernel(
    const float* __restrict__ x,
    const int* __restrict__ d_raw,
    const int* __restrict__ st_h_raw,
    const int* __restrict__ st_w_raw,
    float* __restrict__ out)
{
    const int row_id = blockIdx.x;          // 0 .. B*H-1, one block per image row
    const int b = row_id >> 9;              // / 512
    const int h = row_id & 511;

    // Per-batch params (wave-uniform). One u32 division for the magic
    // reciprocal; every mod after that is mul-based and exact for t < 2^32/d.
    const uint32_t d = (uint32_t)(D1_ + d_raw[b]);      // 96..319
    const uint32_t l = (d + 1u) >> 1;                   // ceil(d * 0.5)
    const uint32_t M = 0xFFFFFFFFu / d + 1u;            // ceil(2^32 / d)

    uint32_t sh = (uint32_t)st_h_raw[b];
    sh -= (uint32_t)(((uint64_t)sh * M) >> 32) * d;     // st_h_raw % d
    uint32_t sw = (uint32_t)st_w_raw[b];
    sw -= (uint32_t)(((uint64_t)sw * M) >> 32) * d;     // st_w_raw % d

    // Row stripe test (uniform per block). +4d keeps the argument positive
    // (OFF+h - sh >= 106 - (d-1) can be negative; 4d > 212 for all d>=96).
    uint32_t ty = (uint32_t)(OFFC + h) + 4u * d - sh;
    ty -= (uint32_t)(((uint64_t)ty * M) >> 32) * d;     // Python-style mod
    const float rmask = (ty < l) ? 0.0f : 1.0f;

    // This thread's 4 consecutive floats within the row: span <= 2 pixels.
    const int e0 = (int)threadIdx.x * 4;                // 0..1532
    const int w0 = e0 / 3;                              // first pixel column

    uint32_t t0 = (uint32_t)(OFFC + w0) + 4u * d - sw;
    t0 -= (uint32_t)(((uint64_t)t0 * M) >> 32) * d;     // in [0, d)
    uint32_t t1 = t0 + 1u;                              // column w0+1, with wrap
    if (t1 >= d) t1 -= d;
    const float cm0 = (t0 < l) ? 0.0f : 1.0f;
    const float cm1 = (t1 < l) ? 0.0f : 1.0f;

    const size_t base = (size_t)row_id * ROW_FLOATS + (size_t)e0;
    float4 v = *(const float4*)(x + base);

    float r[4] = {v.x, v.y, v.z, v.w};
#pragma unroll
    for (int j = 0; j < 4; ++j) {
        const int w = (e0 + j) / 3;                     // const-div -> magic mul
        const float cm = (w == w0) ? cm0 : cm1;
        r[j] *= rmask * cm;
    }
    *(float4*)(out + base) = make_float4(r[0], r[1], r[2], r[3]);
}

extern "C" void kernel_launch(void* const* d_in, const int* in_sizes, int n_in,
                              void* d_out, int out_size, void* d_ws, size_t ws_size,
                              hipStream_t stream) {
    const float* x        = (const float*)d_in[0];
    const int* d_raw      = (const int*)d_in[1];
    const int* st_h_raw   = (const int*)d_in[2];
    const int* st_w_raw   = (const int*)d_in[3];
    float* out            = (float*)d_out;

    const int n_rows = BB * HH_;            // 16384 blocks, one per (b,h) row
    gridmask_kernel<<<n_rows, 384, 0, stream>>>(x, d_raw, st_h_raw, st_w_raw, out);
}